// Round 5
// baseline (466.421 us; speedup 1.0000x reference)
//
#include <hip/hip_runtime.h>

#define BB 8
#define CH 256
#define HH 96
#define WW 192
#define HW (HH*WW)            // 18432
#define ND 25
#define TH 4                  // tile rows per block
#define TW 64                 // tile cols per block
#define S2H 12                // TH + 8 halo
#define S2W 72                // TW + 8 halo
#define S2Q (S2H*S2W/4)       // 216 float4 staging slots
#define NTHR 320              // 5 waves: one dy-group each
#define DPTH 4                // channel prefetch depth (register ring)

// Round-4 geometry (4x64 tile, 5 dy-group waves, shared in2 halo tile in
// double-buffered LDS) + deep software pipeline: raw s_barrier with
// lgkmcnt-only wait (global loads stay in flight across barriers) and a
// depth-4 statically-indexed register prefetch ring for in2-stage and in1.
__global__ __launch_bounds__(NTHR, 4)
void corr_kernel(const float* __restrict__ in1, const float* __restrict__ in2,
                 float* __restrict__ out) {
  __shared__ __align__(16) float s2[2][S2H*S2W];  // 6.9 KB

  const int tile = blockIdx.x;
  const int b    = tile / 72;          // 72 tiles per image (24 x 3)
  const int rem  = tile - b*72;
  const int h0   = (rem / 3) * TH;
  const int w0   = (rem % 3) * TW;
  const int t    = threadIdx.x;
  const int g    = t >> 6;             // dy group 0..4 (one wave each)
  const int lane = t & 63;
  const int r    = lane >> 4;          // 0..3 tile row
  const int c0   = (lane & 15) << 2;   // 0..60 tile col (quad)

  const size_t bplane = (size_t)b * CH * HW;
  const float* in1b = in1 + bplane;
  const float* in2b = in2 + bplane;

  // Staging: threads 0..215 each own one float4 slot of the 12x72 tile.
  const bool stager = t < S2Q;
  const int srow = t / 18, sq = t - (t/18)*18;
  const int gr = h0 + srow - 4, gc = w0 + (sq << 2) - 4;
  const bool sval = stager & ((unsigned)gr < HH) & ((unsigned)gc <= (unsigned)(WW-4));
  const float* src = in2b + (sval ? (gr*WW + gc) : 0);
  const int lofs = srow*S2W + (sq << 2);

  const int rofs = (r + 2*g)*S2W + c0;        // dy row fixed per group
  const float* p1 = in1b + (h0 + r)*WW + (w0 + c0);

  float4 acc[5];
  #pragma unroll
  for (int q = 0; q < 5; ++q) acc[q] = make_float4(0.f, 0.f, 0.f, 0.f);
  const float4 z4 = make_float4(0.f, 0.f, 0.f, 0.f);

  // Prologue: channel 0 straight into LDS buf0; channels 1..DPTH into regs.
  if (stager) {
    float4 x = sval ? *(const float4*)src : z4;
    *(float4*)&s2[0][lofs] = x;
  }
  float4 a = *(const float4*)p1;              // in1 ch 0

  float4 sv[DPTH], an[DPTH];                  // statically indexed only
  #pragma unroll
  for (int j = 0; j < DPTH; ++j) {
    sv[j] = sval ? *(const float4*)(src + (size_t)(1 + j)*HW) : z4;
    an[j] = *(const float4*)(p1 + (size_t)(1 + j)*HW);
  }
  asm volatile("s_waitcnt lgkmcnt(0)" ::: "memory");
  __builtin_amdgcn_s_barrier();

  for (int base = 0; base < CH; base += DPTH) {
    #pragma unroll
    for (int j = 0; j < DPTH; ++j) {
      const int cc = base + j;                // channel being computed
      const int cur = cc & 1;
      // Invariant (same as round 4): reads target s2[cur], writes s2[cur^1],
      // one barrier per iteration separates write(cc) from read(cc+1).
      float4 a_next = an[j];                  // in1 ch cc+1 (loaded D ago)
      // 1) forward staged in2 tile for ch cc+1 into the other buffer
      if (cc + 1 < CH) {
        if (stager) *(float4*)&s2[cur ^ 1][lofs] = sv[j];
      }
      // 2) refill the depth-D ring with channel cc+1+DPTH
      if (cc + 1 + DPTH < CH) {
        const size_t adv = (size_t)(cc + 1 + DPTH) * HW;
        if (sval) sv[j] = *(const float4*)(src + adv);
        an[j] = *(const float4*)(p1 + adv);
      }
      // 3) compute ch cc from current LDS buffer
      {
        const float* rowp = &s2[cur][rofs];
        float wv[12];
        *(float4*)&wv[0] = *(const float4*)(rowp);
        *(float4*)&wv[4] = *(const float4*)(rowp + 4);
        *(float4*)&wv[8] = *(const float4*)(rowp + 8);
        #pragma unroll
        for (int q = 0; q < 5; ++q) {
          float4& A = acc[q];
          A.x = fmaf(a.x, wv[0 + 2*q], A.x);
          A.y = fmaf(a.y, wv[1 + 2*q], A.y);
          A.z = fmaf(a.z, wv[2 + 2*q], A.z);
          A.w = fmaf(a.w, wv[3 + 2*q], A.w);
        }
      }
      a = a_next;
      // LDS-only fence + raw barrier: in-flight global loads survive.
      asm volatile("s_waitcnt lgkmcnt(0)" ::: "memory");
      __builtin_amdgcn_s_barrier();
    }
  }

  // Epilogue: direct final output write, coalesced float4 per disp.
  const float scale = 1.0f / CH;
  float* pout = out + ((size_t)(b*ND + g*5)*HH + (h0 + r))*WW + (w0 + c0);
  #pragma unroll
  for (int q = 0; q < 5; ++q) {
    float4 v;
    v.x = acc[q].x * scale; v.y = acc[q].y * scale;
    v.z = acc[q].z * scale; v.w = acc[q].w * scale;
    *(float4*)(pout + (size_t)q*HW) = v;
  }
}

extern "C" void kernel_launch(void* const* d_in, const int* in_sizes, int n_in,
                              void* d_out, int out_size, void* d_ws, size_t ws_size,
                              hipStream_t stream) {
  const float* in1 = (const float*)d_in[0];
  const float* in2 = (const float*)d_in[1];
  float* out = (float*)d_out;
  corr_kernel<<<dim3(BB * 72), NTHR, 0, stream>>>(in1, in2, out);
}